// Round 18
// baseline (482.989 us; speedup 1.0000x reference)
//
#include <hip/hip_runtime.h>
#include <hip/hip_bf16.h>

#define B_ 64
#define N_ 4096
#define C_ 256
#define K_ 8
#define M_ (B_*N_)
#define ITERS_ 3
#define SCALE_ 0.0625f
#define EPS_ 1e-8f

typedef __attribute__((ext_vector_type(4))) float f32x4;
typedef __attribute__((ext_vector_type(8))) __bf16 bf16x8;
typedef __attribute__((ext_vector_type(8))) unsigned short ushort8;
typedef __attribute__((ext_vector_type(4))) unsigned short ushort4v;

static __device__ __forceinline__ unsigned short f2bf(float f){
    union { float f; unsigned u; } v; v.f = f;
    unsigned r = v.u + 0x7fffu + ((v.u >> 16) & 1u);
    return (unsigned short)(r >> 16);
}
static __device__ __forceinline__ float bf2f(unsigned short h){
    union { unsigned u; float f; } v; v.u = ((unsigned)h) << 16;
    return v.f;
}

// ---------------- prep1: slots init ----------------
__global__ void prep1_kernel(const float* __restrict__ mu, const float* __restrict__ lsig,
                             const float* __restrict__ noise, float* __restrict__ slots){
    int idx = blockIdx.x*256 + threadIdx.x;   // 0..131071
    int c = idx & 255, i = (idx >> 8) & 7;
    slots[idx] = mu[c] + expf(lsig[c])*noise[i*256 + c];
}

// ---------------- prep2: WqkT = Wq@Wk^T, bqt = bq@Wk^T, wqb = Wq@bk, bqk = bq.bk ----------------
__global__ void prep2_kernel(const float* __restrict__ Wq, const float* __restrict__ Wk,
                             const float* __restrict__ bq, const float* __restrict__ bk,
                             float* __restrict__ WqkT, float* __restrict__ bqt,
                             float* __restrict__ wqb, float* __restrict__ bqkv){
    __shared__ float wqrow[256], bkl[256], bql[256];
    __shared__ float red[4], red2[4];
    const int t = threadIdx.x, c = blockIdx.x;
    wqrow[t] = Wq[(size_t)c*256 + t];
    bkl[t] = bk[t];
    bql[t] = bq[t];
    __syncthreads();
    float acc = 0.f, accb = 0.f;
    const float* wkr = Wk + (size_t)t*256;
    #pragma unroll 4
    for (int d = 0; d < 256; d += 4){
        float4 wk4 = *(const float4*)(wkr + d);
        float4 wq4 = *(const float4*)(&wqrow[d]);
        float4 bq4 = *(const float4*)(&bql[d]);
        acc  += wq4.x*wk4.x + wq4.y*wk4.y + wq4.z*wk4.z + wq4.w*wk4.w;
        accb += bq4.x*wk4.x + bq4.y*wk4.y + bq4.z*wk4.z + bq4.w*wk4.w;
    }
    WqkT[(size_t)c*256 + t] = acc;
    if (c == 0) bqt[t] = accb;
    float pw = wqrow[t]*bkl[t];
    float pb = bql[t]*bkl[t];
    #pragma unroll
    for (int m = 1; m < 64; m <<= 1){ pw += __shfl_xor(pw, m); pb += __shfl_xor(pb, m); }
    if ((t & 63) == 0){ red[t >> 6] = pw; red2[t >> 6] = pb; }
    __syncthreads();
    if (t == 0){
        wqb[c] = red[0] + red[1] + red[2] + red[3];
        if (c == 0) bqkv[0] = red2[0] + red2[1] + red2[2] + red2[3];
    }
}

// ---------------- x -> x_hat bf16; layout XH[jt][og(0..7)][rloc(0..255)][32c] ----------------
__global__ void ln_kernel(const float* __restrict__ x, const float* __restrict__ g,
                          const float* __restrict__ bta, unsigned short* __restrict__ XH){
    const int t = threadIdx.x;
    const int row = blockIdx.x*32 + (t >> 3), s = t & 7;
    const float* xr = x + (size_t)row*C_;
    float v[32];
    #pragma unroll
    for (int q = 0; q < 8; ++q)
        *(float4*)&v[q*4] = *(const float4*)(xr + s*4 + q*32);
    float sum = 0.f, sq = 0.f;
    #pragma unroll
    for (int e = 0; e < 32; ++e){ sum += v[e]; sq += v[e]*v[e]; }
    #pragma unroll
    for (int m = 1; m < 8; m <<= 1){ sum += __shfl_xor(sum, m); sq += __shfl_xor(sq, m); }
    float mean = sum * (1.f/256.f);
    float rstd = rsqrtf(sq * (1.f/256.f) - mean*mean + 1e-5f);
    const int jt = row >> 8, rloc = row & 255;
    #pragma unroll
    for (int q = 0; q < 8; ++q){
        float4 g4 = *(const float4*)(g + q*32 + s*4);
        float4 b4 = *(const float4*)(bta + q*32 + s*4);
        ushort4v pk;
        pk[0] = f2bf((v[q*4+0] - mean)*rstd*g4.x + b4.x);
        pk[1] = f2bf((v[q*4+1] - mean)*rstd*g4.y + b4.y);
        pk[2] = f2bf((v[q*4+2] - mean)*rstd*g4.z + b4.z);
        pk[3] = f2bf((v[q*4+3] - mean)*rstd*g4.w + b4.w);
        *(ushort4v*)(XH + (((size_t)jt*8 + q)*256 + rloc)*32 + s*4) = pk;
    }
}

// ---------------- per-iter: slotq = LN_s + q~ (K-staggered weight sweep)  (grid (B,4), 512) ----------------
__global__ __launch_bounds__(512)
void slotq_kernel(const float* __restrict__ slots, const float* __restrict__ WqkT,
                  const float* __restrict__ bqt, const float* __restrict__ wqb,
                  const float* __restrict__ bqkv, const float* __restrict__ gs,
                  const float* __restrict__ bs, float* __restrict__ qtbuf,
                  float* __restrict__ qbb){
    __shared__ float sn[8][260];
    const int t = threadIdx.x, b = blockIdx.x, cgb = blockIdx.y;
    const int i = t >> 6, l = t & 63;
    {
        float4 v4 = *(const float4*)(slots + ((size_t)b*8 + i)*256 + l*4);
        float sum = v4.x + v4.y + v4.z + v4.w;
        float sq  = v4.x*v4.x + v4.y*v4.y + v4.z*v4.z + v4.w*v4.w;
        #pragma unroll
        for (int m = 1; m < 64; m <<= 1){ sum += __shfl_xor(sum, m); sq += __shfl_xor(sq, m); }
        float mean = sum * (1.f/256.f);
        float rstd = rsqrtf(sq * (1.f/256.f) - mean*mean + 1e-5f);
        float4 g4 = *(const float4*)(gs + l*4);
        float4 b4 = *(const float4*)(bs + l*4);
        float n0 = (v4.x - mean)*rstd*g4.x + b4.x;
        float n1 = (v4.y - mean)*rstd*g4.y + b4.y;
        float n2 = (v4.z - mean)*rstd*g4.z + b4.z;
        float n3 = (v4.w - mean)*rstd*g4.w + b4.w;
        sn[i][l*4+0] = n0; sn[i][l*4+1] = n1; sn[i][l*4+2] = n2; sn[i][l*4+3] = n3;
        if (cgb == 0){
            float4 w4 = *(const float4*)(wqb + l*4);
            float pb = n0*w4.x + n1*w4.y + n2*w4.z + n3*w4.w;
            #pragma unroll
            for (int m = 1; m < 64; m <<= 1) pb += __shfl_xor(pb, m);
            if (l == 0) qbb[(size_t)b*8 + i] = SCALE_*(pb + bqkv[0]);
        }
    }
    __syncthreads();
    const int col = cgb*64 + l;
    const int off = (b*8 + i*32) & 255;    // per-(block,wave) K rotation
    float acc = bqt[col];
    #pragma unroll
    for (int cq = 0; cq < 4; ++cq){
        float w[64];
        #pragma unroll
        for (int u = 0; u < 64; ++u){
            int k = (cq*64 + u + off) & 255;
            w[u] = WqkT[(size_t)k*256 + col];
        }
        #pragma unroll
        for (int u = 0; u < 64; ++u){
            int k = (cq*64 + u + off) & 255;
            acc += sn[i][k]*w[u];
        }
    }
    qtbuf[((size_t)b*8 + i)*256 + col] = SCALE_*acc;
}

// ---------------- per-iter: fused attn (unchanged, validated) ----------------
__global__ __launch_bounds__(512)
void attn_kernel(const unsigned short* __restrict__ XH, const float* __restrict__ qt,
                 const float* __restrict__ qb, float* __restrict__ Spart,
                 float* __restrict__ Upart){
    __shared__ __align__(16) unsigned short xs[2*16384];
    __shared__ __align__(16) unsigned short pst[16*72];
    __shared__ float swred[4][8];
    const int t = threadIdx.x, b = blockIdx.x, jb = blockIdx.y;
    const unsigned short* XB = XH + (size_t)(b*16 + jb)*65536;
    const int wv = t >> 6, l = t & 63;
    const int bi = l & 15, kg = l >> 4;
    const bool isQK = (wv < 4), isPV = (wv >= 4);

    bf16x8 bfrag[8];
    float qbl = 0.f;
    {
        const ushort8 zz = (ushort8){0,0,0,0,0,0,0,0};
        #pragma unroll
        for (int ks = 0; ks < 8; ++ks) bfrag[ks] = __builtin_bit_cast(bf16x8, zz);
        if (isQK && bi < 8){
            #pragma unroll
            for (int ks = 0; ks < 8; ++ks){
                const float* qp = qt + ((size_t)b*8 + bi)*256 + ks*32 + kg*8;
                float4 qa = *(const float4*)qp;
                float4 qc = *(const float4*)(qp + 4);
                ushort8 pk;
                pk[0]=f2bf(qa.x); pk[1]=f2bf(qa.y); pk[2]=f2bf(qa.z); pk[3]=f2bf(qa.w);
                pk[4]=f2bf(qc.x); pk[5]=f2bf(qc.y); pk[6]=f2bf(qc.z); pk[7]=f2bf(qc.w);
                bfrag[ks] = __builtin_bit_cast(bf16x8, pk);
            }
            qbl = qb[(size_t)b*8 + bi];
        }
    }
    ushort8 SbA[4], SbB[4];
    const int strow[4] = { (l >> 2), 16 + (l >> 2), 32 + (l >> 2), 48 + (l >> 2) };
    f32x4 acc[4];
    #pragma unroll
    for (int n = 0; n < 4; ++n) acc[n] = (f32x4){0.f,0.f,0.f,0.f};
    const int pv_lo = bi & 7;
    const int pv_sl = (bi >> 3) ^ (kg << 1);
    float s8loc = 0.f;

#define STG_LOAD(Sb, ch) { \
    const unsigned short* gp = XB + (size_t)wv*8192 + (ch)*2048 + l*8; \
    _Pragma("unroll") for (int u = 0; u < 4; ++u) Sb[u] = *(const ushort8*)(gp + u*512); }
#define STG_WRITE(Sb, ch) { \
    unsigned short* xw = &xs[((ch)&1)*16384]; \
    _Pragma("unroll") for (int u = 0; u < 4; ++u){ \
        int rr = strow[u]; \
        int o = (wv*4 + (l & 3)) ^ ((rr & 7) ^ (((rr >> 3) & 3) << 1)); \
        *(ushort8*)&xw[rr*256 + o*8] = Sb[u]; } }
#define BARR() { asm volatile("s_waitcnt lgkmcnt(0)" ::: "memory"); __builtin_amdgcn_s_barrier(); }

#define QK_PHASE(p) if (isQK){ \
    const int cur = ((p)&1)*16384; \
    f32x4 qacc = (f32x4){0.f,0.f,0.f,0.f}; \
    const int rowL = wv*16 + bi; \
    const int swrow = (rowL & 7) ^ (((rowL >> 3) & 3) << 1); \
    const unsigned short* xrow = &xs[cur + rowL*256]; \
    _Pragma("unroll") for (int ks = 0; ks < 8; ++ks){ \
        int chn = (ks*4 + kg) ^ swrow; \
        bf16x8 af = *(const bf16x8*)&xrow[chn*8]; \
        qacc = __builtin_amdgcn_mfma_f32_16x16x32_bf16(af, bfrag[ks], qacc, 0, 0, 0); } \
    ushort4v p4; \
    _Pragma("unroll") for (int rr = 0; rr < 4; ++rr){ \
        float d = qacc[rr] + qbl; \
        float mx = d; \
        mx = fmaxf(mx, __shfl_xor(mx, 1)); \
        mx = fmaxf(mx, __shfl_xor(mx, 2)); \
        mx = fmaxf(mx, __shfl_xor(mx, 4)); \
        float e = __expf(d - mx); \
        float se = e; \
        se += __shfl_xor(se, 1); \
        se += __shfl_xor(se, 2); \
        se += __shfl_xor(se, 4); \
        float pv = e/se + EPS_; \
        p4[rr] = f2bf(pv); \
        if (bi < 8) s8loc += pv; } \
    if (bi < 8) *(ushort4v*)&pst[bi*72 + wv*16 + kg*4] = p4; }

#define PV_PHASE(p) if (isPV){ \
    const int cur = ((p)&1)*16384; \
    _Pragma("unroll") for (int kh = 0; kh < 2; ++kh){ \
        ushort8 pa = *(const ushort8*)&pst[bi*72 + kh*32 + kg*8]; \
        _Pragma("unroll") for (int n = 0; n < 4; ++n){ \
            const int ct2 = ((wv - 4)*4 + n) << 1; \
            ushort8 xv; \
            _Pragma("unroll") for (int e = 0; e < 8; ++e){ \
                int slot = ct2 ^ pv_sl ^ e; \
                xv[e] = xs[cur + kh*8192 + kg*2048 + e*256 + (slot << 3) + pv_lo]; } \
            acc[n] = __builtin_amdgcn_mfma_f32_16x16x32_bf16( \
                __builtin_bit_cast(bf16x8, pa), __builtin_bit_cast(bf16x8, xv), acc[n], 0, 0, 0); } } }

    STG_LOAD(SbA, 0); STG_WRITE(SbA, 0);
    STG_LOAD(SbB, 1);
    BARR();

    STG_LOAD(SbA, 2);
    QK_PHASE(0)
    BARR();
    PV_PHASE(0)
    STG_WRITE(SbB, 1);
    BARR();
    STG_LOAD(SbB, 3);
    QK_PHASE(1)
    BARR();
    PV_PHASE(1)
    STG_WRITE(SbA, 2);
    BARR();
    QK_PHASE(2)
    BARR();
    PV_PHASE(2)
    STG_WRITE(SbB, 3);
    BARR();
    QK_PHASE(3)
    BARR();
    PV_PHASE(3)

    if (isQK){
        float s = s8loc;
        s += __shfl_xor(s, 16);
        s += __shfl_xor(s, 32);
        if (l < 8) swred[wv][l] = s;
    }
    BARR();
    if (t < 8)
        Spart[((size_t)(b*16 + jb))*8 + t] =
            swred[0][t] + swred[1][t] + swred[2][t] + swred[3][t];
    if (isPV && kg < 2){
        #pragma unroll
        for (int n = 0; n < 4; ++n){
            const int ct = (wv - 4)*4 + n;
            #pragma unroll
            for (int r2 = 0; r2 < 4; ++r2){
                int i = kg*4 + r2;
                Upart[(((size_t)(b*16 + jb))*8 + i)*256 + ct*16 + bi] = acc[n][r2];
            }
        }
    }
#undef STG_LOAD
#undef STG_WRITE
#undef BARR
#undef QK_PHASE
#undef PV_PHASE
}

// ---------------- per-iter: slotu1 (K-staggered)  (grid (B,4), 512) ----------------
__global__ __launch_bounds__(512)
void slotu1_kernel(const float* __restrict__ slots, const float* __restrict__ Spart,
                   const float* __restrict__ Upart, const float* __restrict__ Wv,
                   const float* __restrict__ bv, const float* __restrict__ W_ih,
                   const float* __restrict__ b_ih, const float* __restrict__ W_hh,
                   const float* __restrict__ b_hh, float* __restrict__ slots2){
    __shared__ float us[8][260], sp[8][260], upd[8][260];
    const int t = threadIdx.x, b = blockIdx.x, ng = blockIdx.y;
    const int i = t >> 6, l = t & 63;
    {
        float a0 = 0.f, a1 = 0.f, a2 = 0.f, a3 = 0.f, S = 0.f;
        #pragma unroll
        for (int jbl = 0; jbl < 16; ++jbl){
            float4 u4 = *(const float4*)(Upart + (((size_t)(b*16 + jbl))*8 + i)*256 + l*4);
            a0 += u4.x; a1 += u4.y; a2 += u4.z; a3 += u4.w;
            S += Spart[((size_t)(b*16 + jbl))*8 + i];
        }
        float invS = 1.f / S;
        us[i][l*4+0] = a0*invS; us[i][l*4+1] = a1*invS;
        us[i][l*4+2] = a2*invS; us[i][l*4+3] = a3*invS;
        float4 s4 = *(const float4*)(slots + ((size_t)b*8 + i)*256 + l*4);
        sp[i][l*4+0] = s4.x; sp[i][l*4+1] = s4.y; sp[i][l*4+2] = s4.z; sp[i][l*4+3] = s4.w;
    }
    __syncthreads();
    {   // B: upd = us @ Wv + bv (full width), K-staggered chunks of 16
        const int c4 = l*4;
        const int offB = (b*8 + i*32 + ng*64) & 255;
        float4 acc = *(const float4*)(bv + c4);
        #pragma unroll
        for (int cq = 0; cq < 16; ++cq){
            float4 w4[16];
            #pragma unroll
            for (int u = 0; u < 16; ++u){
                int k = (cq*16 + u + offB) & 255;
                w4[u] = *(const float4*)(Wv + (size_t)k*256 + c4);
            }
            #pragma unroll
            for (int u = 0; u < 16; ++u){
                int k = (cq*16 + u + offB) & 255;
                float uv = us[i][k];
                acc.x += uv*w4[u].x; acc.y += uv*w4[u].y;
                acc.z += uv*w4[u].z; acc.w += uv*w4[u].w;
            }
        }
        *(float4*)&upd[i][c4] = acc;
    }
    __syncthreads();
    {   // C: GRU n-slice, K-staggered chunks of 8 (6 streams)
        const int n = ng*64 + l;
        const int offC = (b*8 + i*32 + ng*128) & 255;
        float xr = b_ih[n], xz = b_ih[256+n], xn = b_ih[512+n];
        float hr = b_hh[n], hz = b_hh[256+n], hn = b_hh[512+n];
        #pragma unroll 2
        for (int cq = 0; cq < 32; ++cq){
            float wi0[8], wi1[8], wi2[8], wh0[8], wh1[8], wh2[8];
            #pragma unroll
            for (int u = 0; u < 8; ++u){
                int k = (cq*8 + u + offC) & 255;
                const float* wi = W_ih + (size_t)k*768 + n;
                const float* wh = W_hh + (size_t)k*768 + n;
                wi0[u] = wi[0]; wi1[u] = wi[256]; wi2[u] = wi[512];
                wh0[u] = wh[0]; wh1[u] = wh[256]; wh2[u] = wh[512];
            }
            #pragma unroll
            for (int u = 0; u < 8; ++u){
                int k = (cq*8 + u + offC) & 255;
                float uv = upd[i][k], sv = sp[i][k];
                xr += uv*wi0[u]; xz += uv*wi1[u]; xn += uv*wi2[u];
                hr += sv*wh0[u]; hz += sv*wh1[u]; hn += sv*wh2[u];
            }
        }
        float rv = 1.f/(1.f + __expf(-(xr + hr)));
        float zv = 1.f/(1.f + __expf(-(xz + hz)));
        float nn = tanhf(xn + rv*hn);
        slots2[((size_t)b*8 + i)*256 + n] = (1.f - zv)*nn + zv*sp[i][n];
    }
}

// ---------------- per-iter: slotu2 (K-staggered)  (grid (B,4), 512) ----------------
__global__ __launch_bounds__(512)
void slotu2_kernel(const float* __restrict__ slots2, const float* __restrict__ gf,
                   const float* __restrict__ bf, const float* __restrict__ W1,
                   const float* __restrict__ b1, const float* __restrict__ W2,
                   const float* __restrict__ b2, float* __restrict__ slots,
                   float* __restrict__ dout){
    __shared__ float s0[8][260], pre[8][260], hb[8][260];
    const int t = threadIdx.x, b = blockIdx.x, ng = blockIdx.y;
    const int i = t >> 6, l = t & 63;
    {
        float4 v4 = *(const float4*)(slots2 + ((size_t)b*8 + i)*256 + l*4);
        float sum = v4.x + v4.y + v4.z + v4.w;
        float sq  = v4.x*v4.x + v4.y*v4.y + v4.z*v4.z + v4.w*v4.w;
        #pragma unroll
        for (int m = 1; m < 64; m <<= 1){ sum += __shfl_xor(sum, m); sq += __shfl_xor(sq, m); }
        float mean = sum * (1.f/256.f);
        float rstd = rsqrtf(sq * (1.f/256.f) - mean*mean + 1e-5f);
        float4 g4 = *(const float4*)(gf + l*4);
        float4 b4 = *(const float4*)(bf + l*4);
        s0[i][l*4+0] = v4.x; s0[i][l*4+1] = v4.y; s0[i][l*4+2] = v4.z; s0[i][l*4+3] = v4.w;
        pre[i][l*4+0] = (v4.x - mean)*rstd*g4.x + b4.x;
        pre[i][l*4+1] = (v4.y - mean)*rstd*g4.y + b4.y;
        pre[i][l*4+2] = (v4.z - mean)*rstd*g4.z + b4.z;
        pre[i][l*4+3] = (v4.w - mean)*rstd*g4.w + b4.w;
    }
    __syncthreads();
    {   // E: h = relu(pre @ W1 + b1), full width, K-staggered chunks of 16
        const int h4 = l*4;
        const int offE = (b*8 + i*32 + ng*64) & 255;
        float4 acc = *(const float4*)(b1 + h4);
        #pragma unroll
        for (int cq = 0; cq < 16; ++cq){
            float4 w4[16];
            #pragma unroll
            for (int u = 0; u < 16; ++u){
                int k = (cq*16 + u + offE) & 255;
                w4[u] = *(const float4*)(W1 + (size_t)k*256 + h4);
            }
            #pragma unroll
            for (int u = 0; u < 16; ++u){
                int k = (cq*16 + u + offE) & 255;
                float pv = pre[i][k];
                acc.x += pv*w4[u].x; acc.y += pv*w4[u].y;
                acc.z += pv*w4[u].z; acc.w += pv*w4[u].w;
            }
        }
        hb[i][h4+0] = fmaxf(acc.x, 0.f); hb[i][h4+1] = fmaxf(acc.y, 0.f);
        hb[i][h4+2] = fmaxf(acc.z, 0.f); hb[i][h4+3] = fmaxf(acc.w, 0.f);
    }
    __syncthreads();
    {   // F: out = s0 + h @ W2 + b2, n-slice, K-staggered chunks of 64
        const int n = ng*64 + l;
        const int offF = (b*8 + i*32) & 255;
        float acc = b2[n];
        #pragma unroll
        for (int cq = 0; cq < 4; ++cq){
            float w[64];
            #pragma unroll
            for (int u = 0; u < 64; ++u){
                int k = (cq*64 + u + offF) & 255;
                w[u] = W2[(size_t)k*256 + n];
            }
            #pragma unroll
            for (int u = 0; u < 64; ++u){
                int k = (cq*64 + u + offF) & 255;
                acc += hb[i][k]*w[u];
            }
        }
        float val = s0[i][n] + acc;
        size_t off = ((size_t)b*8 + i)*256 + n;
        slots[off] = val;
        dout[off]  = val;
    }
}

extern "C" void kernel_launch(void* const* d_in, const int* in_sizes, int n_in,
                              void* d_out, int out_size, void* d_ws, size_t ws_size,
                              hipStream_t stream){
    const float* inputs = (const float*)d_in[0];
    const float* noise  = (const float*)d_in[1];
    const float* mu     = (const float*)d_in[2];
    const float* lsig   = (const float*)d_in[3];
    const float* g_in   = (const float*)d_in[4];
    const float* b_in   = (const float*)d_in[5];
    const float* g_s    = (const float*)d_in[6];
    const float* b_s    = (const float*)d_in[7];
    const float* g_ff   = (const float*)d_in[8];
    const float* b_ff   = (const float*)d_in[9];
    const float* Wq     = (const float*)d_in[10];
    const float* bq     = (const float*)d_in[11];
    const float* Wk     = (const float*)d_in[12];
    const float* bk     = (const float*)d_in[13];
    const float* Wv     = (const float*)d_in[14];
    const float* bv     = (const float*)d_in[15];
    const float* W_ih   = (const float*)d_in[16];
    const float* b_ih   = (const float*)d_in[17];
    const float* W_hh   = (const float*)d_in[18];
    const float* b_hh   = (const float*)d_in[19];
    const float* W1     = (const float*)d_in[20];
    const float* b1     = (const float*)d_in[21];
    const float* W2     = (const float*)d_in[22];
    const float* b2     = (const float*)d_in[23];

    char* ws = (char*)d_ws;
    unsigned short* XH  = (unsigned short*)(ws);               // 128 MB
    float* Upart        = (float*)(ws + ((size_t)128 << 20));  // 8 MB
    float* Spart        = (float*)(ws + ((size_t)136 << 20));  // 8 KB
    float* qtbuf        = (float*)(ws + ((size_t)137 << 20));  // 512 KB
    float* qbb          = (float*)(ws + ((size_t)138 << 20));  // 2 KB
    float* slots        = (float*)(ws + ((size_t)139 << 20));  // 512 KB
    float* slots2       = (float*)(ws + ((size_t)140 << 20));  // 512 KB
    float* WqkT         = (float*)(ws + ((size_t)141 << 20));  // 256 KB
    float* bqt          = (float*)(ws + ((size_t)142 << 20));  // 1 KB
    float* wqb          = (float*)(ws + ((size_t)143 << 20));  // 1 KB
    float* bqkv         = (float*)(ws + ((size_t)144 << 20));  // 4 B

    prep1_kernel<<<512, 256, 0, stream>>>(mu, lsig, noise, slots);
    prep2_kernel<<<256, 256, 0, stream>>>(Wq, Wk, bq, bk, WqkT, bqt, wqb, bqkv);
    ln_kernel<<<M_/32, 256, 0, stream>>>(inputs, g_in, b_in, XH);
    for (int it = 0; it < ITERS_; ++it){
        slotq_kernel<<<dim3(B_, 4), 512, 0, stream>>>(slots, WqkT, bqt, wqb, bqkv,
                                                      g_s, b_s, qtbuf, qbb);
        attn_kernel<<<dim3(B_, 16), 512, 0, stream>>>(XH, qtbuf, qbb, Spart, Upart);
        slotu1_kernel<<<dim3(B_, 4), 512, 0, stream>>>(slots, Spart, Upart, Wv, bv,
                                                       W_ih, b_ih, W_hh, b_hh, slots2);
        slotu2_kernel<<<dim3(B_, 4), 512, 0, stream>>>(slots2, g_ff, b_ff, W1, b1, W2, b2,
                                                       slots, (float*)d_out);
    }
}

// Round 19
// 454.080 us; speedup vs baseline: 1.0637x; 1.0637x over previous
//
#include <hip/hip_runtime.h>
#include <hip/hip_bf16.h>

#define B_ 64
#define N_ 4096
#define C_ 256
#define K_ 8
#define M_ (B_*N_)
#define ITERS_ 3
#define SCALE_ 0.0625f
#define EPS_ 1e-8f

typedef __attribute__((ext_vector_type(4))) float f32x4;
typedef __attribute__((ext_vector_type(8))) __bf16 bf16x8;
typedef __attribute__((ext_vector_type(8))) unsigned short ushort8;
typedef __attribute__((ext_vector_type(4))) unsigned short ushort4v;

static __device__ __forceinline__ unsigned short f2bf(float f){
    union { float f; unsigned u; } v; v.f = f;
    unsigned r = v.u + 0x7fffu + ((v.u >> 16) & 1u);
    return (unsigned short)(r >> 16);
}
static __device__ __forceinline__ float bf2f(unsigned short h){
    union { unsigned u; float f; } v; v.u = ((unsigned)h) << 16;
    return v.f;
}

// ---------------- prep (merged): WqkT/bqt/wqb/bqkv + slots init ----------------
__global__ void prep_kernel(const float* __restrict__ Wq, const float* __restrict__ Wk,
                            const float* __restrict__ bq, const float* __restrict__ bk,
                            const float* __restrict__ mu, const float* __restrict__ lsig,
                            const float* __restrict__ noise,
                            float* __restrict__ WqkT, float* __restrict__ bqt,
                            float* __restrict__ wqb, float* __restrict__ bqkv,
                            float* __restrict__ slots){
    __shared__ float wqrow[256], bkl[256], bql[256];
    __shared__ float red[4], red2[4];
    const int t = threadIdx.x, c = blockIdx.x;
    // slots init: two elements per thread (256 blocks x 256 thr x 2 = 131072)
    {
        int idx = c*256 + t;
        #pragma unroll
        for (int h = 0; h < 2; ++h){
            int id2 = idx + h*65536;
            int sc = id2 & 255, si = (id2 >> 8) & 7;
            slots[id2] = mu[sc] + expf(lsig[sc])*noise[si*256 + sc];
        }
    }
    wqrow[t] = Wq[(size_t)c*256 + t];
    bkl[t] = bk[t];
    bql[t] = bq[t];
    __syncthreads();
    float acc = 0.f, accb = 0.f;
    const float* wkr = Wk + (size_t)t*256;
    #pragma unroll 4
    for (int d = 0; d < 256; d += 4){
        float4 wk4 = *(const float4*)(wkr + d);
        float4 wq4 = *(const float4*)(&wqrow[d]);
        float4 bq4 = *(const float4*)(&bql[d]);
        acc  += wq4.x*wk4.x + wq4.y*wk4.y + wq4.z*wk4.z + wq4.w*wk4.w;
        accb += bq4.x*wk4.x + bq4.y*wk4.y + bq4.z*wk4.z + bq4.w*wk4.w;
    }
    WqkT[(size_t)c*256 + t] = acc;
    if (c == 0) bqt[t] = accb;
    float pw = wqrow[t]*bkl[t];
    float pb = bql[t]*bkl[t];
    #pragma unroll
    for (int m = 1; m < 64; m <<= 1){ pw += __shfl_xor(pw, m); pb += __shfl_xor(pb, m); }
    if ((t & 63) == 0){ red[t >> 6] = pw; red2[t >> 6] = pb; }
    __syncthreads();
    if (t == 0){
        wqb[c] = red[0] + red[1] + red[2] + red[3];
        if (c == 0) bqkv[0] = red2[0] + red2[1] + red2[2] + red2[3];
    }
}

// ---------------- x -> x_hat bf16; layout XH[jt][og(0..7)][rloc(0..255)][32c] ----------------
// Lane map: lane s owns 16B pieces at s*16B + q*128B -> contiguous read/write instructions.
__global__ void ln_kernel(const float* __restrict__ x, const float* __restrict__ g,
                          const float* __restrict__ bta, unsigned short* __restrict__ XH){
    const int t = threadIdx.x;
    const int row = blockIdx.x*32 + (t >> 3), s = t & 7;
    const float* xr = x + (size_t)row*C_;
    float v[32];
    #pragma unroll
    for (int q = 0; q < 8; ++q)
        *(float4*)&v[q*4] = *(const float4*)(xr + s*4 + q*32);
    float sum = 0.f, sq = 0.f;
    #pragma unroll
    for (int e = 0; e < 32; ++e){ sum += v[e]; sq += v[e]*v[e]; }
    #pragma unroll
    for (int m = 1; m < 8; m <<= 1){ sum += __shfl_xor(sum, m); sq += __shfl_xor(sq, m); }
    float mean = sum * (1.f/256.f);
    float rstd = rsqrtf(sq * (1.f/256.f) - mean*mean + 1e-5f);
    const int jt = row >> 8, rloc = row & 255;
    #pragma unroll
    for (int q = 0; q < 8; ++q){
        float4 g4 = *(const float4*)(g + q*32 + s*4);
        float4 b4 = *(const float4*)(bta + q*32 + s*4);
        ushort4v pk;
        pk[0] = f2bf((v[q*4+0] - mean)*rstd*g4.x + b4.x);
        pk[1] = f2bf((v[q*4+1] - mean)*rstd*g4.y + b4.y);
        pk[2] = f2bf((v[q*4+2] - mean)*rstd*g4.z + b4.z);
        pk[3] = f2bf((v[q*4+3] - mean)*rstd*g4.w + b4.w);
        *(ushort4v*)(XH + (((size_t)jt*8 + q)*256 + rloc)*32 + s*4) = pk;
    }
}

// ---------------- per-iter: slotq = LN_s + q~ = SCALE*(sn@Wqk + bqt), qb  (grid (B,4), 512) ----------------
__global__ void slotq_kernel(const float* __restrict__ slots, const float* __restrict__ WqkT,
                             const float* __restrict__ bqt, const float* __restrict__ wqb,
                             const float* __restrict__ bqkv, const float* __restrict__ gs,
                             const float* __restrict__ bs, float* __restrict__ qtbuf,
                             float* __restrict__ qbb){
    __shared__ float sn[8][260];
    const int t = threadIdx.x, b = blockIdx.x, cgb = blockIdx.y;
    const int i = t >> 6, l = t & 63;
    {
        float4 v4 = *(const float4*)(slots + ((size_t)b*8 + i)*256 + l*4);
        float sum = v4.x + v4.y + v4.z + v4.w;
        float sq  = v4.x*v4.x + v4.y*v4.y + v4.z*v4.z + v4.w*v4.w;
        #pragma unroll
        for (int m = 1; m < 64; m <<= 1){ sum += __shfl_xor(sum, m); sq += __shfl_xor(sq, m); }
        float mean = sum * (1.f/256.f);
        float rstd = rsqrtf(sq * (1.f/256.f) - mean*mean + 1e-5f);
        float4 g4 = *(const float4*)(gs + l*4);
        float4 b4 = *(const float4*)(bs + l*4);
        float n0 = (v4.x - mean)*rstd*g4.x + b4.x;
        float n1 = (v4.y - mean)*rstd*g4.y + b4.y;
        float n2 = (v4.z - mean)*rstd*g4.z + b4.z;
        float n3 = (v4.w - mean)*rstd*g4.w + b4.w;
        sn[i][l*4+0] = n0; sn[i][l*4+1] = n1; sn[i][l*4+2] = n2; sn[i][l*4+3] = n3;
        if (cgb == 0){
            float4 w4 = *(const float4*)(wqb + l*4);
            float pb = n0*w4.x + n1*w4.y + n2*w4.z + n3*w4.w;
            #pragma unroll
            for (int m = 1; m < 64; m <<= 1) pb += __shfl_xor(pb, m);
            if (l == 0) qbb[(size_t)b*8 + i] = SCALE_*(pb + bqkv[0]);
        }
    }
    __syncthreads();
    const int col = cgb*64 + l;
    float acc = bqt[col];
    #pragma unroll
    for (int cb = 0; cb < 256; cb += 64){
        float w[64];
        #pragma unroll
        for (int u = 0; u < 64; ++u) w[u] = WqkT[(size_t)(cb+u)*256 + col];
        #pragma unroll
        for (int u = 0; u < 64; ++u) acc += sn[i][cb+u]*w[u];
    }
    qtbuf[((size_t)b*8 + i)*256 + col] = SCALE_*acc;
}

// ---------------- per-iter: fused attn v3 — wave-specialized pipeline, raw barriers ----------------
// grid (B,16), 512 threads = 8 waves. Waves 0-1: QK MFMA + softmax; 2-3: staging; 4-7: PV MFMA.
// LDS: 4-deep ring of 32row x 256c swizzled chunks (64KB) + 2-deep pst.
// Swizzle: row j stores c-slot o at (o ^ SW(j)), SW(j) = (j&7) ^ (((j>>3)&3)<<1).
// Staging lane map: lane = r16*4 + u4 -> every global load instr covers 1KB contiguous.
__global__ __launch_bounds__(512)
void attn_kernel(const unsigned short* __restrict__ XH, const float* __restrict__ qt,
                 const float* __restrict__ qb, float* __restrict__ Spart,
                 float* __restrict__ Upart){
    __shared__ __align__(16) unsigned short xs[4*8192];
    __shared__ __align__(16) unsigned short pst[2][16*40];
    __shared__ float swred[2][8];
    const int t = threadIdx.x, b = blockIdx.x, jb = blockIdx.y;
    const unsigned short* XB = XH + (size_t)(b*16 + jb)*65536;
    const int wv = t >> 6, l = t & 63;
    const int bi = l & 15, kg = l >> 4;
    const bool isQK = (wv < 2), isST = (wv == 2 || wv == 3), isPV = (wv >= 4);

    // --- QK setup: q~ B-fragments in registers ---
    bf16x8 bfrag[8];
    float qbl = 0.f;
    {
        const ushort8 zz = (ushort8){0,0,0,0,0,0,0,0};
        #pragma unroll
        for (int ks = 0; ks < 8; ++ks) bfrag[ks] = __builtin_bit_cast(bf16x8, zz);
        if (isQK && bi < 8){
            #pragma unroll
            for (int ks = 0; ks < 8; ++ks){
                const float* qp = qt + ((size_t)b*8 + bi)*256 + ks*32 + kg*8;
                float4 qa = *(const float4*)qp;
                float4 qc = *(const float4*)(qp + 4);
                ushort8 pk;
                pk[0]=f2bf(qa.x); pk[1]=f2bf(qa.y); pk[2]=f2bf(qa.z); pk[3]=f2bf(qa.w);
                pk[4]=f2bf(qc.x); pk[5]=f2bf(qc.y); pk[6]=f2bf(qc.z); pk[7]=f2bf(qc.w);
                bfrag[ks] = __builtin_bit_cast(bf16x8, pk);
            }
            qbl = qb[(size_t)b*8 + bi];
        }
    }
    // --- staging setup (waves 2-3): lane (r16 = l>>2, u4 = l&3); rows (wv&1)*16 + r16 ---
    const int rstg = (wv & 1)*16 + (l >> 2);
    const int u4 = l & 3;
    const int swrr = (rstg & 7) ^ (((rstg >> 3) & 3) << 1);
    ushort8 S[8];
    // --- PV setup (waves 4-7): c-tiles ct = (wv-4)*4 + n ---
    f32x4 acc[4];
    #pragma unroll
    for (int n = 0; n < 4; ++n) acc[n] = (f32x4){0.f,0.f,0.f,0.f};
    const int pv_lo = bi & 7;
    const int pv_sl = (bi >> 3) ^ (kg << 1);
    float s8loc = 0.f;

#define STG_LOAD(ch) { \
    _Pragma("unroll") for (int og = 0; og < 8; ++og) \
        S[og] = *(const ushort8*)(XB + ((size_t)og*256 + (ch)*32 + rstg)*32 + u4*8); }
#define STG_WRITE(ch) { \
    unsigned short* xw = &xs[((ch)&3)*8192 + rstg*256]; \
    _Pragma("unroll") for (int og = 0; og < 8; ++og) \
        *(ushort8*)&xw[(((og*4 + u4) ^ swrr)*8)] = S[og]; }
#define BARR() { asm volatile("s_waitcnt lgkmcnt(0)" ::: "memory"); __builtin_amdgcn_s_barrier(); }

    // prologue: fill buf0; loads for ch1 in S entering loop
    if (isST){
        STG_LOAD(0); STG_WRITE(0);
        STG_LOAD(1);
    }
    BARR();   // buf0 visible

    #pragma unroll
    for (int p = 0; p < 8; ++p){
        // PV(p-1): waves 4-7
        if (isPV && p >= 1){
            const int cur = ((p-1) & 3) * 8192;
            ushort8 pa = *(const ushort8*)&pst[(p-1) & 1][bi*40 + kg*8];
            #pragma unroll
            for (int n = 0; n < 4; ++n){
                const int ct2 = ((wv - 4)*4 + n) << 1;
                ushort8 xv;
                #pragma unroll
                for (int e = 0; e < 8; ++e){
                    int slot = ct2 ^ pv_sl ^ e;
                    xv[e] = xs[cur + kg*2048 + e*256 + (slot << 3) + pv_lo];
                }
                acc[n] = __builtin_amdgcn_mfma_f32_16x16x32_bf16(
                    __builtin_bit_cast(bf16x8, pa), __builtin_bit_cast(bf16x8, xv), acc[n], 0, 0, 0);
            }
        }
        // QK(p): waves 0-1
        if (isQK){
            const int cur = (p & 3) * 8192;
            f32x4 qacc = (f32x4){0.f,0.f,0.f,0.f};
            const int rowL = wv*16 + bi;
            const int swrow = (rowL & 7) ^ (((rowL >> 3) & 3) << 1);
            const unsigned short* xrow = &xs[cur + rowL*256];
            #pragma unroll
            for (int ks = 0; ks < 8; ++ks){
                int chn = (ks*4 + kg) ^ swrow;
                bf16x8 af = *(const bf16x8*)&xrow[chn*8];
                qacc = __builtin_amdgcn_mfma_f32_16x16x32_bf16(af, bfrag[ks], qacc, 0, 0, 0);
            }
            ushort4v p4;
            #pragma unroll
            for (int rr = 0; rr < 4; ++rr){
                float d = qacc[rr] + qbl;
                float mx = d;
                mx = fmaxf(mx, __shfl_xor(mx, 1));
                mx = fmaxf(mx, __shfl_xor(mx, 2));
                mx = fmaxf(mx, __shfl_xor(mx, 4));
                float e = __expf(d - mx);
                float se = e;
                se += __shfl_xor(se, 1);
                se += __shfl_xor(se, 2);
                se += __shfl_xor(se, 4);
                float pv = e/se + EPS_;
                p4[rr] = f2bf(pv);
                if (bi < 8) s8loc += pv;
            }
            if (bi < 8)
                *(ushort4v*)&pst[p & 1][bi*40 + wv*16 + kg*4] = p4;
        }
        // staging: write buf p+1 (loads issued last iter), issue loads for p+2
        if (isST){
            if (p + 1 <= 7) STG_WRITE(p + 1);
            if (p + 2 <= 7) STG_LOAD(p + 2);
        }
        BARR();
    }
    // epilogue: PV(7)
    if (isPV){
        const int cur = (7 & 3) * 8192;
        ushort8 pa = *(const ushort8*)&pst[7 & 1][bi*40 + kg*8];
        #pragma unroll
        for (int n = 0; n < 4; ++n){
            const int ct2 = ((wv - 4)*4 + n) << 1;
            ushort8 xv;
            #pragma unroll
            for (int e = 0; e < 8; ++e){
                int slot = ct2 ^ pv_sl ^ e;
                xv[e] = xs[cur + kg*2048 + e*256 + (slot << 3) + pv_lo];
            }
            acc[n] = __builtin_amdgcn_mfma_f32_16x16x32_bf16(
                __builtin_bit_cast(bf16x8, pa), __builtin_bit_cast(bf16x8, xv), acc[n], 0, 0, 0);
        }
    }
    // Spart from QK waves
    if (isQK){
        float s = s8loc;
        s += __shfl_xor(s, 16);
        s += __shfl_xor(s, 32);
        if (l < 8) swred[wv][l] = s;
    }
    BARR();
    if (t < 8)
        Spart[((size_t)(b*16 + jb))*8 + t] = swred[0][t] + swred[1][t];
    // Upart from PV D-fragments: lane i = kg*4+r2 (kg<2), c = ct*16+bi
    if (isPV && kg < 2){
        #pragma unroll
        for (int n = 0; n < 4; ++n){
            const int ct = (wv - 4)*4 + n;
            #pragma unroll
            for (int r2 = 0; r2 < 4; ++r2){
                int i = kg*4 + r2;
                Upart[(((size_t)(b*16 + jb))*8 + i)*256 + ct*16 + bi] = acc[n][r2];
            }
        }
    }
#undef STG_LOAD
#undef STG_WRITE
#undef BARR
}

// ---------------- per-iter: slotu1 = Upart reduce + Wv GEMM + GRU n-slice  (grid (B,4), 512) ----------------
__global__ void slotu1_kernel(const float* __restrict__ slots, const float* __restrict__ Spart,
                              const float* __restrict__ Upart, const float* __restrict__ Wv,
                              const float* __restrict__ bv, const float* __restrict__ W_ih,
                              const float* __restrict__ b_ih, const float* __restrict__ W_hh,
                              const float* __restrict__ b_hh, float* __restrict__ slots2){
    __shared__ float us[8][260], sp[8][260], upd[8][260];
    const int t = threadIdx.x, b = blockIdx.x, ng = blockIdx.y;
    const int i = t >> 6, l = t & 63;
    {
        float a0 = 0.f, a1 = 0.f, a2 = 0.f, a3 = 0.f, S = 0.f;
        #pragma unroll
        for (int jbl = 0; jbl < 16; ++jbl){
            float4 u4 = *(const float4*)(Upart + (((size_t)(b*16 + jbl))*8 + i)*256 + l*4);
            a0 += u4.x; a1 += u4.y; a2 += u4.z; a3 += u4.w;
            S += Spart[((size_t)(b*16 + jbl))*8 + i];
        }
        float invS = 1.f / S;
        us[i][l*4+0] = a0*invS; us[i][l*4+1] = a1*invS;
        us[i][l*4+2] = a2*invS; us[i][l*4+3] = a3*invS;
        float4 s4 = *(const float4*)(slots + ((size_t)b*8 + i)*256 + l*4);
        sp[i][l*4+0] = s4.x; sp[i][l*4+1] = s4.y; sp[i][l*4+2] = s4.z; sp[i][l*4+3] = s4.w;
    }
    __syncthreads();
    {   // upd = us @ Wv + bv (full width, redundant across ng blocks), chunked streaming
        const int c4 = l*4;
        float4 acc = *(const float4*)(bv + c4);
        #pragma unroll
        for (int cb = 0; cb < 256; cb += 16){
            float4 w4[16];
            #pragma unroll
            for (int u = 0; u < 16; ++u)
                w4[u] = *(const float4*)(Wv + (size_t)(cb+u)*256 + c4);
            #pragma unroll
            for (int u = 0; u < 16; ++u){
                float uv = us[i][cb+u];
                acc.x += uv*w4[u].x; acc.y += uv*w4[u].y;
                acc.z += uv*w4[u].z; acc.w += uv*w4[u].w;
            }
        }
        *(float4*)&upd[i][c4] = acc;
    }
    __syncthreads();
    {   // GRU for n-slice, 6 streams chunked 8 deep
        const int n = ng*64 + l;
        float xr = b_ih[n], xz = b_ih[256+n], xn = b_ih[512+n];
        float hr = b_hh[n], hz = b_hh[256+n], hn = b_hh[512+n];
        #pragma unroll 2
        for (int cb = 0; cb < 256; cb += 8){
            float wi0[8], wi1[8], wi2[8], wh0[8], wh1[8], wh2[8];
            #pragma unroll
            for (int u = 0; u < 8; ++u){
                const float* wi = W_ih + (size_t)(cb+u)*768 + n;
                const float* wh = W_hh + (size_t)(cb+u)*768 + n;
                wi0[u] = wi[0]; wi1[u] = wi[256]; wi2[u] = wi[512];
                wh0[u] = wh[0]; wh1[u] = wh[256]; wh2[u] = wh[512];
            }
            #pragma unroll
            for (int u = 0; u < 8; ++u){
                float uv = upd[i][cb+u], sv = sp[i][cb+u];
                xr += uv*wi0[u]; xz += uv*wi1[u]; xn += uv*wi2[u];
                hr += sv*wh0[u]; hz += sv*wh1[u]; hn += sv*wh2[u];
            }
        }
        float rv = 1.f/(1.f + __expf(-(xr + hr)));
        float zv = 1.f/(1.f + __expf(-(xz + hz)));
        float nn = tanhf(xn + rv*hn);
        slots2[((size_t)b*8 + i)*256 + n] = (1.f - zv)*nn + zv*sp[i][n];
    }
}

// ---------------- per-iter: slotu2 = LN_ff + FFN1 + FFN2 n-slice  (grid (B,4), 512) ----------------
__global__ void slotu2_kernel(const float* __restrict__ slots2, const float* __restrict__ gf,
                              const float* __restrict__ bf, const float* __restrict__ W1,
                              const float* __restrict__ b1, const float* __restrict__ W2,
                              const float* __restrict__ b2, float* __restrict__ slots,
                              float* __restrict__ dout){
    __shared__ float s0[8][260], pre[8][260], hb[8][260];
    const int t = threadIdx.x, b = blockIdx.x, ng = blockIdx.y;
    const int i = t >> 6, l = t & 63;
    {
        float4 v4 = *(const float4*)(slots2 + ((size_t)b*8 + i)*256 + l*4);
        float sum = v4.x + v4.y + v4.z + v4.w;
        float sq  = v4.x*v4.x + v4.y*v4.y + v4.z*v4.z + v4.w*v4.w;
        #pragma unroll
        for (int m = 1; m < 64; m <<= 1){ sum += __shfl_xor(sum, m); sq += __shfl_xor(sq, m); }
        float mean = sum * (1.f/256.f);
        float rstd = rsqrtf(sq * (1.f/256.f) - mean*mean + 1e-5f);
        float4 g4 = *(const float4*)(gf + l*4);
        float4 b4 = *(const float4*)(bf + l*4);
        s0[i][l*4+0] = v4.x; s0[i][l*4+1] = v4.y; s0[i][l*4+2] = v4.z; s0[i][l*4+3] = v4.w;
        pre[i][l*4+0] = (v4.x - mean)*rstd*g4.x + b4.x;
        pre[i][l*4+1] = (v4.y - mean)*rstd*g4.y + b4.y;
        pre[i][l*4+2] = (v4.z - mean)*rstd*g4.z + b4.z;
        pre[i][l*4+3] = (v4.w - mean)*rstd*g4.w + b4.w;
    }
    __syncthreads();
    {   // h = relu(pre @ W1 + b1) (full width, redundant), chunked streaming
        const int h4 = l*4;
        float4 acc = *(const float4*)(b1 + h4);
        #pragma unroll
        for (int cb = 0; cb < 256; cb += 16){
            float4 w4[16];
            #pragma unroll
            for (int u = 0; u < 16; ++u)
                w4[u] = *(const float4*)(W1 + (size_t)(cb+u)*256 + h4);
            #pragma unroll
            for (int u = 0; u < 16; ++u){
                float pv = pre[i][cb+u];
                acc.x += pv*w4[u].x; acc.y += pv*w4[u].y;
                acc.z += pv*w4[u].z; acc.w += pv*w4[u].w;
            }
        }
        hb[i][h4+0] = fmaxf(acc.x, 0.f); hb[i][h4+1] = fmaxf(acc.y, 0.f);
        hb[i][h4+2] = fmaxf(acc.z, 0.f); hb[i][h4+3] = fmaxf(acc.w, 0.f);
    }
    __syncthreads();
    {   // out = s0 + h @ W2 + b2, n-slice, chunked streaming
        const int n = ng*64 + l;
        float acc = b2[n];
        #pragma unroll
        for (int mb = 0; mb < 256; mb += 64){
            float w[64];
            #pragma unroll
            for (int u = 0; u < 64; ++u) w[u] = W2[(size_t)(mb+u)*256 + n];
            #pragma unroll
            for (int u = 0; u < 64; ++u) acc += hb[i][mb+u]*w[u];
        }
        float val = s0[i][n] + acc;
        size_t off = ((size_t)b*8 + i)*256 + n;
        slots[off] = val;
        dout[off]  = val;
    }
}

extern "C" void kernel_launch(void* const* d_in, const int* in_sizes, int n_in,
                              void* d_out, int out_size, void* d_ws, size_t ws_size,
                              hipStream_t stream){
    const float* inputs = (const float*)d_in[0];
    const float* noise  = (const float*)d_in[1];
    const float* mu     = (const float*)d_in[2];
    const float* lsig   = (const float*)d_in[3];
    const float* g_in   = (const float*)d_in[4];
    const float* b_in   = (const float*)d_in[5];
    const float* g_s    = (const float*)d_in[6];
    const float* b_s    = (const float*)d_in[7];
    const float* g_ff   = (const float*)d_in[8];
    const float* b_ff   = (const float*)d_in[9];
    const float* Wq     = (const float*)d_in[10];
    const float* bq     = (const float*)d_in[11];
    const float* Wk     = (const float*)d_in[12];
    const float* bk     = (const float*)d_in[13];
    const float* Wv     = (const float*)d_in[14];
    const float* bv     = (const float*)d_in[15];
    const float* W_ih   = (const float*)d_in[16];
    const float* b_ih   = (const float*)d_in[17];
    const float* W_hh   = (const float*)d_in[18];
    const float* b_hh   = (const float*)d_in[19];
    const float* W1     = (const float*)d_in[20];
    const float* b1     = (const float*)d_in[21];
    const float* W2     = (const float*)d_in[22];
    const float* b2     = (const float*)d_in[23];

    char* ws = (char*)d_ws;
    unsigned short* XH  = (unsigned short*)(ws);               // 128 MB
    float* Upart        = (float*)(ws + ((size_t)128 << 20));  // 8 MB
    float* Spart        = (float*)(ws + ((size_t)136 << 20));  // 8 KB
    float* qtbuf        = (float*)(ws + ((size_t)137 << 20));  // 512 KB
    float* qbb          = (float*)(ws + ((size_t)138 << 20));  // 2 KB
    float* slots        = (float*)(ws + ((size_t)139 << 20));  // 512 KB
    float* slots2       = (float*)(ws + ((size_t)140 << 20));  // 512 KB
    float* WqkT         = (float*)(ws + ((size_t)141 << 20));  // 256 KB
    float* bqt          = (float*)(ws + ((size_t)142 << 20));  // 1 KB
    float* wqb          = (float*)(ws + ((size_t)143 << 20));  // 1 KB
    float* bqkv         = (float*)(ws + ((size_t)144 << 20));  // 4 B

    prep_kernel<<<256, 256, 0, stream>>>(Wq, Wk, bq, bk, mu, lsig, noise,
                                         WqkT, bqt, wqb, bqkv, slots);
    ln_kernel<<<M_/32, 256, 0, stream>>>(inputs, g_in, b_in, XH);
    for (int it = 0; it < ITERS_; ++it){
        slotq_kernel<<<dim3(B_, 4), 512, 0, stream>>>(slots, WqkT, bqt, wqb, bqkv,
                                                      g_s, b_s, qtbuf, qbb);
        attn_kernel<<<dim3(B_, 16), 512, 0, stream>>>(XH, qtbuf, qbb, Spart, Upart);
        slotu1_kernel<<<dim3(B_, 4), 512, 0, stream>>>(slots, Spart, Upart, Wv, bv,
                                                       W_ih, b_ih, W_hh, b_hh, slots2);
        slotu2_kernel<<<dim3(B_, 4), 512, 0, stream>>>(slots2, g_ff, b_ff, W1, b1, W2, b2,
                                                       slots, (float*)d_out);
    }
}

// Round 21
// 426.543 us; speedup vs baseline: 1.1323x; 1.0646x over previous
//
#include <hip/hip_runtime.h>
#include <hip/hip_bf16.h>

#define B_ 64
#define N_ 4096
#define C_ 256
#define K_ 8
#define M_ (B_*N_)
#define ITERS_ 3
#define SCALE_ 0.0625f
#define EPS_ 1e-8f

typedef __attribute__((ext_vector_type(4))) float f32x4;
typedef __attribute__((ext_vector_type(8))) __bf16 bf16x8;
typedef __attribute__((ext_vector_type(8))) unsigned short ushort8;
typedef __attribute__((ext_vector_type(4))) unsigned short ushort4v;

static __device__ __forceinline__ unsigned short f2bf(float f){
    union { float f; unsigned u; } v; v.f = f;
    unsigned r = v.u + 0x7fffu + ((v.u >> 16) & 1u);
    return (unsigned short)(r >> 16);
}
static __device__ __forceinline__ float bf2f(unsigned short h){
    union { unsigned u; float f; } v; v.u = ((unsigned)h) << 16;
    return v.f;
}

// ---------------- prep (merged): WqkT/bqt/wqb/bqkv + slots init ----------------
__global__ void prep_kernel(const float* __restrict__ Wq, const float* __restrict__ Wk,
                            const float* __restrict__ bq, const float* __restrict__ bk,
                            const float* __restrict__ mu, const float* __restrict__ lsig,
                            const float* __restrict__ noise,
                            float* __restrict__ WqkT, float* __restrict__ bqt,
                            float* __restrict__ wqb, float* __restrict__ bqkv,
                            float* __restrict__ slots){
    __shared__ float wqrow[256], bkl[256], bql[256];
    __shared__ float red[4], red2[4];
    const int t = threadIdx.x, c = blockIdx.x;
    {
        int idx = c*256 + t;
        #pragma unroll
        for (int h = 0; h < 2; ++h){
            int id2 = idx + h*65536;
            int sc = id2 & 255, si = (id2 >> 8) & 7;
            slots[id2] = mu[sc] + expf(lsig[sc])*noise[si*256 + sc];
        }
    }
    wqrow[t] = Wq[(size_t)c*256 + t];
    bkl[t] = bk[t];
    bql[t] = bq[t];
    __syncthreads();
    float acc = 0.f, accb = 0.f;
    const float* wkr = Wk + (size_t)t*256;
    #pragma unroll 4
    for (int d = 0; d < 256; d += 4){
        float4 wk4 = *(const float4*)(wkr + d);
        float4 wq4 = *(const float4*)(&wqrow[d]);
        float4 bq4 = *(const float4*)(&bql[d]);
        acc  += wq4.x*wk4.x + wq4.y*wk4.y + wq4.z*wk4.z + wq4.w*wk4.w;
        accb += bq4.x*wk4.x + bq4.y*wk4.y + bq4.z*wk4.z + bq4.w*wk4.w;
    }
    WqkT[(size_t)c*256 + t] = acc;
    if (c == 0) bqt[t] = accb;
    float pw = wqrow[t]*bkl[t];
    float pb = bql[t]*bkl[t];
    #pragma unroll
    for (int m = 1; m < 64; m <<= 1){ pw += __shfl_xor(pw, m); pb += __shfl_xor(pb, m); }
    if ((t & 63) == 0){ red[t >> 6] = pw; red2[t >> 6] = pb; }
    __syncthreads();
    if (t == 0){
        wqb[c] = red[0] + red[1] + red[2] + red[3];
        if (c == 0) bqkv[0] = red2[0] + red2[1] + red2[2] + red2[3];
    }
}

// ---------------- x -> x_hat bf16; layout XH[jt][og(0..7)][rloc(0..255)][32c] ----------------
// Non-temporal x reads + XH writes (ext-vector types): keep the 384MB stream out of L2.
__global__ void ln_kernel(const float* __restrict__ x, const float* __restrict__ g,
                          const float* __restrict__ bta, unsigned short* __restrict__ XH){
    const int t = threadIdx.x;
    const int row = blockIdx.x*32 + (t >> 3), s = t & 7;
    const float* xr = x + (size_t)row*C_;
    float v[32];
    #pragma unroll
    for (int q = 0; q < 8; ++q){
        f32x4 xv = __builtin_nontemporal_load((const f32x4*)(xr + s*4 + q*32));
        v[q*4+0] = xv[0]; v[q*4+1] = xv[1]; v[q*4+2] = xv[2]; v[q*4+3] = xv[3];
    }
    float sum = 0.f, sq = 0.f;
    #pragma unroll
    for (int e = 0; e < 32; ++e){ sum += v[e]; sq += v[e]*v[e]; }
    #pragma unroll
    for (int m = 1; m < 8; m <<= 1){ sum += __shfl_xor(sum, m); sq += __shfl_xor(sq, m); }
    float mean = sum * (1.f/256.f);
    float rstd = rsqrtf(sq * (1.f/256.f) - mean*mean + 1e-5f);
    const int jt = row >> 8, rloc = row & 255;
    #pragma unroll
    for (int q = 0; q < 8; ++q){
        float4 g4 = *(const float4*)(g + q*32 + s*4);
        float4 b4 = *(const float4*)(bta + q*32 + s*4);
        ushort4v pk;
        pk[0] = f2bf((v[q*4+0] - mean)*rstd*g4.x + b4.x);
        pk[1] = f2bf((v[q*4+1] - mean)*rstd*g4.y + b4.y);
        pk[2] = f2bf((v[q*4+2] - mean)*rstd*g4.z + b4.z);
        pk[3] = f2bf((v[q*4+3] - mean)*rstd*g4.w + b4.w);
        __builtin_nontemporal_store(pk, (ushort4v*)(XH + (((size_t)jt*8 + q)*256 + rloc)*32 + s*4));
    }
}

// ---------------- per-iter: slotq = LN_s + q~ = SCALE*(sn@Wqk + bqt), qb  (grid (B,4), 512) ----------------
__global__ void slotq_kernel(const float* __restrict__ slots, const float* __restrict__ WqkT,
                             const float* __restrict__ bqt, const float* __restrict__ wqb,
                             const float* __restrict__ bqkv, const float* __restrict__ gs,
                             const float* __restrict__ bs, float* __restrict__ qtbuf,
                             float* __restrict__ qbb){
    __shared__ float sn[8][260];
    const int t = threadIdx.x, b = blockIdx.x, cgb = blockIdx.y;
    const int i = t >> 6, l = t & 63;
    {
        float4 v4 = *(const float4*)(slots + ((size_t)b*8 + i)*256 + l*4);
        float sum = v4.x + v4.y + v4.z + v4.w;
        float sq  = v4.x*v4.x + v4.y*v4.y + v4.z*v4.z + v4.w*v4.w;
        #pragma unroll
        for (int m = 1; m < 64; m <<= 1){ sum += __shfl_xor(sum, m); sq += __shfl_xor(sq, m); }
        float mean = sum * (1.f/256.f);
        float rstd = rsqrtf(sq * (1.f/256.f) - mean*mean + 1e-5f);
        float4 g4 = *(const float4*)(gs + l*4);
        float4 b4 = *(const float4*)(bs + l*4);
        float n0 = (v4.x - mean)*rstd*g4.x + b4.x;
        float n1 = (v4.y - mean)*rstd*g4.y + b4.y;
        float n2 = (v4.z - mean)*rstd*g4.z + b4.z;
        float n3 = (v4.w - mean)*rstd*g4.w + b4.w;
        sn[i][l*4+0] = n0; sn[i][l*4+1] = n1; sn[i][l*4+2] = n2; sn[i][l*4+3] = n3;
        if (cgb == 0){
            float4 w4 = *(const float4*)(wqb + l*4);
            float pb = n0*w4.x + n1*w4.y + n2*w4.z + n3*w4.w;
            #pragma unroll
            for (int m = 1; m < 64; m <<= 1) pb += __shfl_xor(pb, m);
            if (l == 0) qbb[(size_t)b*8 + i] = SCALE_*(pb + bqkv[0]);
        }
    }
    __syncthreads();
    const int col = cgb*64 + l;
    float acc = bqt[col];
    #pragma unroll
    for (int cb = 0; cb < 256; cb += 64){
        float w[64];
        #pragma unroll
        for (int u = 0; u < 64; ++u) w[u] = WqkT[(size_t)(cb+u)*256 + col];
        #pragma unroll
        for (int u = 0; u < 64; ++u) acc += sn[i][cb+u]*w[u];
    }
    qtbuf[((size_t)b*8 + i)*256 + col] = SCALE_*acc;
}

// ---------------- per-iter: fused attn v3 — wave-specialized pipeline, NT staging loads ----------------
__global__ __launch_bounds__(512)
void attn_kernel(const unsigned short* __restrict__ XH, const float* __restrict__ qt,
                 const float* __restrict__ qb, float* __restrict__ Spart,
                 float* __restrict__ Upart){
    __shared__ __align__(16) unsigned short xs[4*8192];
    __shared__ __align__(16) unsigned short pst[2][16*40];
    __shared__ float swred[2][8];
    const int t = threadIdx.x, b = blockIdx.x, jb = blockIdx.y;
    const unsigned short* XB = XH + (size_t)(b*16 + jb)*65536;
    const int wv = t >> 6, l = t & 63;
    const int bi = l & 15, kg = l >> 4;
    const bool isQK = (wv < 2), isST = (wv == 2 || wv == 3), isPV = (wv >= 4);

    bf16x8 bfrag[8];
    float qbl = 0.f;
    {
        const ushort8 zz = (ushort8){0,0,0,0,0,0,0,0};
        #pragma unroll
        for (int ks = 0; ks < 8; ++ks) bfrag[ks] = __builtin_bit_cast(bf16x8, zz);
        if (isQK && bi < 8){
            #pragma unroll
            for (int ks = 0; ks < 8; ++ks){
                const float* qp = qt + ((size_t)b*8 + bi)*256 + ks*32 + kg*8;
                float4 qa = *(const float4*)qp;
                float4 qc = *(const float4*)(qp + 4);
                ushort8 pk;
                pk[0]=f2bf(qa.x); pk[1]=f2bf(qa.y); pk[2]=f2bf(qa.z); pk[3]=f2bf(qa.w);
                pk[4]=f2bf(qc.x); pk[5]=f2bf(qc.y); pk[6]=f2bf(qc.z); pk[7]=f2bf(qc.w);
                bfrag[ks] = __builtin_bit_cast(bf16x8, pk);
            }
            qbl = qb[(size_t)b*8 + bi];
        }
    }
    const int rstg = (wv & 1)*16 + (l >> 2);
    const int u4 = l & 3;
    const int swrr = (rstg & 7) ^ (((rstg >> 3) & 3) << 1);
    ushort8 S[8];
    f32x4 acc[4];
    #pragma unroll
    for (int n = 0; n < 4; ++n) acc[n] = (f32x4){0.f,0.f,0.f,0.f};
    const int pv_lo = bi & 7;
    const int pv_sl = (bi >> 3) ^ (kg << 1);
    float s8loc = 0.f;

#define STG_LOAD(ch) { \
    _Pragma("unroll") for (int og = 0; og < 8; ++og) \
        S[og] = __builtin_nontemporal_load((const ushort8*)(XB + ((size_t)og*256 + (ch)*32 + rstg)*32 + u4*8)); }
#define STG_WRITE(ch) { \
    unsigned short* xw = &xs[((ch)&3)*8192 + rstg*256]; \
    _Pragma("unroll") for (int og = 0; og < 8; ++og) \
        *(ushort8*)&xw[(((og*4 + u4) ^ swrr)*8)] = S[og]; }
#define BARR() { asm volatile("s_waitcnt lgkmcnt(0)" ::: "memory"); __builtin_amdgcn_s_barrier(); }

    if (isST){
        STG_LOAD(0); STG_WRITE(0);
        STG_LOAD(1);
    }
    BARR();

    #pragma unroll
    for (int p = 0; p < 8; ++p){
        if (isPV && p >= 1){
            const int cur = ((p-1) & 3) * 8192;
            ushort8 pa = *(const ushort8*)&pst[(p-1) & 1][bi*40 + kg*8];
            #pragma unroll
            for (int n = 0; n < 4; ++n){
                const int ct2 = ((wv - 4)*4 + n) << 1;
                ushort8 xv;
                #pragma unroll
                for (int e = 0; e < 8; ++e){
                    int slot = ct2 ^ pv_sl ^ e;
                    xv[e] = xs[cur + kg*2048 + e*256 + (slot << 3) + pv_lo];
                }
                acc[n] = __builtin_amdgcn_mfma_f32_16x16x32_bf16(
                    __builtin_bit_cast(bf16x8, pa), __builtin_bit_cast(bf16x8, xv), acc[n], 0, 0, 0);
            }
        }
        if (isQK){
            const int cur = (p & 3) * 8192;
            f32x4 qacc = (f32x4){0.f,0.f,0.f,0.f};
            const int rowL = wv*16 + bi;
            const int swrow = (rowL & 7) ^ (((rowL >> 3) & 3) << 1);
            const unsigned short* xrow = &xs[cur + rowL*256];
            #pragma unroll
            for (int ks = 0; ks < 8; ++ks){
                int chn = (ks*4 + kg) ^ swrow;
                bf16x8 af = *(const bf16x8*)&xrow[chn*8];
                qacc = __builtin_amdgcn_mfma_f32_16x16x32_bf16(af, bfrag[ks], qacc, 0, 0, 0);
            }
            ushort4v p4;
            #pragma unroll
            for (int rr = 0; rr < 4; ++rr){
                float d = qacc[rr] + qbl;
                float mx = d;
                mx = fmaxf(mx, __shfl_xor(mx, 1));
                mx = fmaxf(mx, __shfl_xor(mx, 2));
                mx = fmaxf(mx, __shfl_xor(mx, 4));
                float e = __expf(d - mx);
                float se = e;
                se += __shfl_xor(se, 1);
                se += __shfl_xor(se, 2);
                se += __shfl_xor(se, 4);
                float pv = e/se + EPS_;
                p4[rr] = f2bf(pv);
                if (bi < 8) s8loc += pv;
            }
            if (bi < 8)
                *(ushort4v*)&pst[p & 1][bi*40 + wv*16 + kg*4] = p4;
        }
        if (isST){
            if (p + 1 <= 7) STG_WRITE(p + 1);
            if (p + 2 <= 7) STG_LOAD(p + 2);
        }
        BARR();
    }
    if (isPV){
        const int cur = (7 & 3) * 8192;
        ushort8 pa = *(const ushort8*)&pst[7 & 1][bi*40 + kg*8];
        #pragma unroll
        for (int n = 0; n < 4; ++n){
            const int ct2 = ((wv - 4)*4 + n) << 1;
            ushort8 xv;
            #pragma unroll
            for (int e = 0; e < 8; ++e){
                int slot = ct2 ^ pv_sl ^ e;
                xv[e] = xs[cur + kg*2048 + e*256 + (slot << 3) + pv_lo];
            }
            acc[n] = __builtin_amdgcn_mfma_f32_16x16x32_bf16(
                __builtin_bit_cast(bf16x8, pa), __builtin_bit_cast(bf16x8, xv), acc[n], 0, 0, 0);
        }
    }
    if (isQK){
        float s = s8loc;
        s += __shfl_xor(s, 16);
        s += __shfl_xor(s, 32);
        if (l < 8) swred[wv][l] = s;
    }
    BARR();
    if (t < 8)
        Spart[((size_t)(b*16 + jb))*8 + t] = swred[0][t] + swred[1][t];
    if (isPV && kg < 2){
        #pragma unroll
        for (int n = 0; n < 4; ++n){
            const int ct = (wv - 4)*4 + n;
            #pragma unroll
            for (int r2 = 0; r2 < 4; ++r2){
                int i = kg*4 + r2;
                Upart[(((size_t)(b*16 + jb))*8 + i)*256 + ct*16 + bi] = acc[n][r2];
            }
        }
    }
#undef STG_LOAD
#undef STG_WRITE
#undef BARR
}

// ---------------- per-iter: slotu1 = Upart reduce + Wv GEMM + GRU n-slice  (grid (B,4), 512) ----------------
__global__ void slotu1_kernel(const float* __restrict__ slots, const float* __restrict__ Spart,
                              const float* __restrict__ Upart, const float* __restrict__ Wv,
                              const float* __restrict__ bv, const float* __restrict__ W_ih,
                              const float* __restrict__ b_ih, const float* __restrict__ W_hh,
                              const float* __restrict__ b_hh, float* __restrict__ slots2){
    __shared__ float us[8][260], sp[8][260], upd[8][260];
    const int t = threadIdx.x, b = blockIdx.x, ng = blockIdx.y;
    const int i = t >> 6, l = t & 63;
    {
        float a0 = 0.f, a1 = 0.f, a2 = 0.f, a3 = 0.f, S = 0.f;
        #pragma unroll
        for (int jbl = 0; jbl < 16; ++jbl){
            float4 u4 = *(const float4*)(Upart + (((size_t)(b*16 + jbl))*8 + i)*256 + l*4);
            a0 += u4.x; a1 += u4.y; a2 += u4.z; a3 += u4.w;
            S += Spart[((size_t)(b*16 + jbl))*8 + i];
        }
        float invS = 1.f / S;
        us[i][l*4+0] = a0*invS; us[i][l*4+1] = a1*invS;
        us[i][l*4+2] = a2*invS; us[i][l*4+3] = a3*invS;
        float4 s4 = *(const float4*)(slots + ((size_t)b*8 + i)*256 + l*4);
        sp[i][l*4+0] = s4.x; sp[i][l*4+1] = s4.y; sp[i][l*4+2] = s4.z; sp[i][l*4+3] = s4.w;
    }
    __syncthreads();
    {
        const int c4 = l*4;
        float4 acc = *(const float4*)(bv + c4);
        #pragma unroll
        for (int cb = 0; cb < 256; cb += 16){
            float4 w4[16];
            #pragma unroll
            for (int u = 0; u < 16; ++u)
                w4[u] = *(const float4*)(Wv + (size_t)(cb+u)*256 + c4);
            #pragma unroll
            for (int u = 0; u < 16; ++u){
                float uv = us[i][cb+u];
                acc.x += uv*w4[u].x; acc.y += uv*w4[u].y;
                acc.z += uv*w4[u].z; acc.w += uv*w4[u].w;
            }
        }
        *(float4*)&upd[i][c4] = acc;
    }
    __syncthreads();
    {
        const int n = ng*64 + l;
        float xr = b_ih[n], xz = b_ih[256+n], xn = b_ih[512+n];
        float hr = b_hh[n], hz = b_hh[256+n], hn = b_hh[512+n];
        #pragma unroll 2
        for (int cb = 0; cb < 256; cb += 8){
            float wi0[8], wi1[8], wi2[8], wh0[8], wh1[8], wh2[8];
            #pragma unroll
            for (int u = 0; u < 8; ++u){
                const float* wi = W_ih + (size_t)(cb+u)*768 + n;
                const float* wh = W_hh + (size_t)(cb+u)*768 + n;
                wi0[u] = wi[0]; wi1[u] = wi[256]; wi2[u] = wi[512];
                wh0[u] = wh[0]; wh1[u] = wh[256]; wh2[u] = wh[512];
            }
            #pragma unroll
            for (int u = 0; u < 8; ++u){
                float uv = upd[i][cb+u], sv = sp[i][cb+u];
                xr += uv*wi0[u]; xz += uv*wi1[u]; xn += uv*wi2[u];
                hr += sv*wh0[u]; hz += sv*wh1[u]; hn += sv*wh2[u];
            }
        }
        float rv = 1.f/(1.f + __expf(-(xr + hr)));
        float zv = 1.f/(1.f + __expf(-(xz + hz)));
        float nn = tanhf(xn + rv*hn);
        slots2[((size_t)b*8 + i)*256 + n] = (1.f - zv)*nn + zv*sp[i][n];
    }
}

// ---------------- per-iter: slotu2 = LN_ff + FFN1 + FFN2 n-slice  (grid (B,4), 512) ----------------
__global__ void slotu2_kernel(const float* __restrict__ slots2, const float* __restrict__ gf,
                              const float* __restrict__ bf, const float* __restrict__ W1,
                              const float* __restrict__ b1, const float* __restrict__ W2,
                              const float* __restrict__ b2, float* __restrict__ slots,
                              float* __restrict__ dout){
    __shared__ float s0[8][260], pre[8][260], hb[8][260];
    const int t = threadIdx.x, b = blockIdx.x, ng = blockIdx.y;
    const int i = t >> 6, l = t & 63;
    {
        float4 v4 = *(const float4*)(slots2 + ((size_t)b*8 + i)*256 + l*4);
        float sum = v4.x + v4.y + v4.z + v4.w;
        float sq  = v4.x*v4.x + v4.y*v4.y + v4.z*v4.z + v4.w*v4.w;
        #pragma unroll
        for (int m = 1; m < 64; m <<= 1){ sum += __shfl_xor(sum, m); sq += __shfl_xor(sq, m); }
        float mean = sum * (1.f/256.f);
        float rstd = rsqrtf(sq * (1.f/256.f) - mean*mean + 1e-5f);
        float4 g4 = *(const float4*)(gf + l*4);
        float4 b4 = *(const float4*)(bf + l*4);
        s0[i][l*4+0] = v4.x; s0[i][l*4+1] = v4.y; s0[i][l*4+2] = v4.z; s0[i][l*4+3] = v4.w;
        pre[i][l*4+0] = (v4.x - mean)*rstd*g4.x + b4.x;
        pre[i][l*4+1] = (v4.y - mean)*rstd*g4.y + b4.y;
        pre[i][l*4+2] = (v4.z - mean)*rstd*g4.z + b4.z;
        pre[i][l*4+3] = (v4.w - mean)*rstd*g4.w + b4.w;
    }
    __syncthreads();
    {
        const int h4 = l*4;
        float4 acc = *(const float4*)(b1 + h4);
        #pragma unroll
        for (int cb = 0; cb < 256; cb += 16){
            float4 w4[16];
            #pragma unroll
            for (int u = 0; u < 16; ++u)
                w4[u] = *(const float4*)(W1 + (size_t)(cb+u)*256 + h4);
            #pragma unroll
            for (int u = 0; u < 16; ++u){
                float pv = pre[i][cb+u];
                acc.x += pv*w4[u].x; acc.y += pv*w4[u].y;
                acc.z += pv*w4[u].z; acc.w += pv*w4[u].w;
            }
        }
        hb[i][h4+0] = fmaxf(acc.x, 0.f); hb[i][h4+1] = fmaxf(acc.y, 0.f);
        hb[i][h4+2] = fmaxf(acc.z, 0.f); hb[i][h4+3] = fmaxf(acc.w, 0.f);
    }
    __syncthreads();
    {
        const int n = ng*64 + l;
        float acc = b2[n];
        #pragma unroll
        for (int mb = 0; mb < 256; mb += 64){
            float w[64];
            #pragma unroll
            for (int u = 0; u < 64; ++u) w[u] = W2[(size_t)(mb+u)*256 + n];
            #pragma unroll
            for (int u = 0; u < 64; ++u) acc += hb[i][mb+u]*w[u];
        }
        float val = s0[i][n] + acc;
        size_t off = ((size_t)b*8 + i)*256 + n;
        slots[off] = val;
        dout[off]  = val;
    }
}

extern "C" void kernel_launch(void* const* d_in, const int* in_sizes, int n_in,
                              void* d_out, int out_size, void* d_ws, size_t ws_size,
                              hipStream_t stream){
    const float* inputs = (const float*)d_in[0];
    const float* noise  = (const float*)d_in[1];
    const float* mu     = (const float*)d_in[2];
    const float* lsig   = (const float*)d_in[3];
    const float* g_in   = (const float*)d_in[4];
    const float* b_in   = (const float*)d_in[5];
    const float* g_s    = (const float*)d_in[6];
    const float* b_s    = (const float*)d_in[7];
    const float* g_ff   = (const float*)d_in[8];
    const float* b_ff   = (const float*)d_in[9];
    const float* Wq     = (const float*)d_in[10];
    const float* bq     = (const float*)d_in[11];
    const float* Wk     = (const float*)d_in[12];
    const float* bk     = (const float*)d_in[13];
    const float* Wv     = (const float*)d_in[14];
    const float* bv     = (const float*)d_in[15];
    const float* W_ih   = (const float*)d_in[16];
    const float* b_ih   = (const float*)d_in[17];
    const float* W_hh   = (const float*)d_in[18];
    const float* b_hh   = (const float*)d_in[19];
    const float* W1     = (const float*)d_in[20];
    const float* b1     = (const float*)d_in[21];
    const float* W2     = (const float*)d_in[22];
    const float* b2     = (const float*)d_in[23];

    char* ws = (char*)d_ws;
    unsigned short* XH  = (unsigned short*)(ws);               // 128 MB
    float* Upart        = (float*)(ws + ((size_t)128 << 20));  // 8 MB
    float* Spart        = (float*)(ws + ((size_t)136 << 20));  // 8 KB
    float* qtbuf        = (float*)(ws + ((size_t)137 << 20));  // 512 KB
    float* qbb          = (float*)(ws + ((size_t)138 << 20));  // 2 KB
    float* slots        = (float*)(ws + ((size_t)139 << 20));  // 512 KB
    float* slots2       = (float*)(ws + ((size_t)140 << 20));  // 512 KB
    float* WqkT         = (float*)(ws + ((size_t)141 << 20));  // 256 KB
    float* bqt          = (float*)(ws + ((size_t)142 << 20));  // 1 KB
    float* wqb          = (float*)(ws + ((size_t)143 << 20));  // 1 KB
    float* bqkv         = (float*)(ws + ((size_t)144 << 20));  // 4 B

    prep_kernel<<<256, 256, 0, stream>>>(Wq, Wk, bq, bk, mu, lsig, noise,
                                         WqkT, bqt, wqb, bqkv, slots);
    ln_kernel<<<M_/32, 256, 0, stream>>>(inputs, g_in, b_in, XH);
    for (int it = 0; it < ITERS_; ++it){
        slotq_kernel<<<dim3(B_, 4), 512, 0, stream>>>(slots, WqkT, bqt, wqb, bqkv,
                                                      g_s, b_s, qtbuf, qbb);
        attn_kernel<<<dim3(B_, 16), 512, 0, stream>>>(XH, qtbuf, qbb, Spart, Upart);
        slotu1_kernel<<<dim3(B_, 4), 512, 0, stream>>>(slots, Spart, Upart, Wv, bv,
                                                       W_ih, b_ih, W_hh, b_hh, slots2);
        slotu2_kernel<<<dim3(B_, 4), 512, 0, stream>>>(slots2, g_ff, b_ff, W1, b1, W2, b2,
                                                       slots, (float*)d_out);
    }
}